// Round 8
// baseline (195.306 us; speedup 1.0000x reference)
//
#include <hip/hip_runtime.h>
#include <math.h>

#define BATCH_N   32768
#define IN_F      784
#define HID_F     256
#define NCLS      10
#define BM        128         // batch rows per block
#define NTHREADS  1024        // 16 waves: rg = wv>>3 (2 row groups), ct = wv&7

typedef __attribute__((ext_vector_type(8)))  short short8;   // 8 bf16 = one 32x32x16 operand frag
typedef __attribute__((ext_vector_type(4)))  float f32x4;
typedef __attribute__((ext_vector_type(16))) float f32x16;   // 32x32 accumulator

// d_ws: w1 as split-bf16 frag images for 32x32x16 B-operand (verified r6/r7):
//   slot s = (kt*8 + ct)*64 + lane, 16 B: elems j=0..7 =
//   w1[ct*32 + (lane&31)][kt*16 + (lane>>5)*8 + j]   (784 = 49*16: no padding)
#define WS_W1H 0
#define WS_W1L 401408          // 49*8*64*16

union S8U { short8 s; uint4 u; };

__device__ __forceinline__ void cvt8(float4 a, float4 b, short8* hi, short8* lo) {
    const unsigned M = 0xFFFF0000u;
    const unsigned ux = __float_as_uint(a.x), uy = __float_as_uint(a.y),
                   uz = __float_as_uint(a.z), uw = __float_as_uint(a.w),
                   vx = __float_as_uint(b.x), vy = __float_as_uint(b.y),
                   vz = __float_as_uint(b.z), vw = __float_as_uint(b.w);
    S8U h, l;
    h.u.x = (ux >> 16) | (uy & M);
    h.u.y = (uz >> 16) | (uw & M);
    h.u.z = (vx >> 16) | (vy & M);
    h.u.w = (vz >> 16) | (vw & M);
    const float rx = a.x - __uint_as_float(ux & M);
    const float ry = a.y - __uint_as_float(uy & M);
    const float rz = a.z - __uint_as_float(uz & M);
    const float rw = a.w - __uint_as_float(uw & M);
    const float sx = b.x - __uint_as_float(vx & M);
    const float sy = b.y - __uint_as_float(vy & M);
    const float sz = b.z - __uint_as_float(vz & M);
    const float sw_ = b.w - __uint_as_float(vw & M);
    l.u.x = (__float_as_uint(rx) >> 16) | (__float_as_uint(ry) & M);
    l.u.y = (__float_as_uint(rz) >> 16) | (__float_as_uint(rw) & M);
    l.u.z = (__float_as_uint(sx) >> 16) | (__float_as_uint(sy) & M);
    l.u.w = (__float_as_uint(sz) >> 16) | (__float_as_uint(sw_) & M);
    *hi = h.s; *lo = l.s;
}

__device__ __forceinline__ void cvt8v(f32x4 a, f32x4 b, short8* hi, short8* lo) {
    float4 fa = make_float4(a[0], a[1], a[2], a[3]);
    float4 fb = make_float4(b[0], b[1], b[2], b[3]);
    cvt8(fa, fb, hi, lo);
}

// ---- pre-pass: w1 -> split-bf16 32-wide frag images (verified r6/r7) ----
__global__ __launch_bounds__(256)
void prep_w1_kernel(const float* __restrict__ w1, char* __restrict__ ws) {
    const int s    = blockIdx.x * 256 + threadIdx.x;   // 49*8*64 = 25088, grid 98
    const int lane = s & 63, ct = (s >> 6) & 7, kt = s >> 9;
    const int n    = ct * 32 + (lane & 31);
    const int k0   = kt * 16 + (lane >> 5) * 8;
    const float* p = w1 + (size_t)n * IN_F + k0;
    const float4 a = *(const float4*)p;
    const float4 b = *(const float4*)(p + 4);
    short8 hi, lo;
    cvt8(a, b, &hi, &lo);
    *(short8*)(ws + WS_W1H + (size_t)s * 16) = hi;
    *(short8*)(ws + WS_W1L + (size_t)s * 16) = lo;
}

// inline-asm 16B loads; results consumed only after the matching manual vmcnt,
// and NEVER copied between registers while in flight (r5 contract).
__device__ __forceinline__ short8 gload_s8(const void* p) {
    short8 r;
    asm volatile("global_load_dwordx4 %0, %1, off" : "=v"(r) : "v"(p));
    return r;
}
__device__ __forceinline__ f32x4 gload_f4(const float* p) {
    f32x4 r;
    asm volatile("global_load_dwordx4 %0, %1, off" : "=v"(r) : "v"(p));
    return r;
}

#define MFMA32(A, B, C) __builtin_amdgcn_mfma_f32_32x32x16_bf16((A), (B), (C), 0, 0, 0)

// one K-tile: wave reads its 2 row-tiles (hi+lo images) and does 6 MFMAs.
// read addr: rb{0,1} + ((T ^ txor) << 5); conflict-free by layout construction.
#define MFMA_KT(BUF, T, BH, BL)                                                \
    {                                                                          \
        const short8 ah0 = *(const short8*)((BUF) + rb0 + (((T) ^ txor) << 5));\
        const short8 al0 = *(const short8*)((BUF) + 16384 + rb0 + (((T) ^ txor) << 5)); \
        const short8 ah1 = *(const short8*)((BUF) + rb1 + (((T) ^ txor) << 5));\
        const short8 al1 = *(const short8*)((BUF) + 16384 + rb1 + (((T) ^ txor) << 5)); \
        __builtin_amdgcn_s_setprio(1);                                         \
        acc0 = MFMA32(ah0, BH, acc0);                                          \
        acc0 = MFMA32(al0, BH, acc0);                                          \
        acc0 = MFMA32(ah0, BL, acc0);                                          \
        acc1 = MFMA32(ah1, BH, acc1);                                          \
        acc1 = MFMA32(al1, BH, acc1);                                          \
        acc1 = MFMA32(ah1, BL, acc1);                                          \
        __builtin_amdgcn_s_setprio(0);                                         \
    }

// x issue for next round window (2 chunks of 4 floats = this thread's 8 floats)
#define XISSUE(G) do {                                                         \
        s0 = gload_f4(xs + ((G) + 1) * 64 + sc * 8);                           \
        s1 = gload_f4(xs + ((G) + 1) * 64 + sc * 8 + 4);                       \
    } while (0)
// tail round (16 valid k): clamped uniform loads; only sc<2 threads write
#define XISSUET() do {                                                         \
        s0 = gload_f4(xs + 768 + shf * 8);                                     \
        s1 = gload_f4(xs + 768 + shf * 8 + 4);                                 \
    } while (0)
// convert staged x (8 floats -> 1 hi + 1 lo b128 write, conflict-free layout)
#define CVT4W(BW) do {                                                         \
        short8 h0, l0;                                                         \
        cvt8v(s0, s1, &h0, &l0);                                               \
        *(short8*)((BW) + wo)         = h0;                                    \
        *(short8*)((BW) + 16384 + wo) = l0;                                    \
    } while (0)
#define CVTTW(BW) do {                                                         \
        short8 h0, l0;                                                         \
        cvt8v(s0, s1, &h0, &l0);                                               \
        if (sc < 2) {                                                          \
            *(short8*)((BW) + wot)         = h0;                               \
            *(short8*)((BW) + 16384 + wot) = l0;                               \
        }                                                                      \
    } while (0)

// Round of 4 kt. Entry invariant: outstanding VMEM = [B(4G): 2 loads].
// Ledger (oldest-first, 2 B loads/kt, 2 x loads at t1):
//  t0: +B1    -> 4          ; vmcnt(2) retires B0  ; compute kt0 (E)
//  t1: +B2,+x -> 6          ; vmcnt(4) retires B1  ; compute kt1 (O)
//  t2: +B3    -> 6          ; vmcnt(4) retires B2  ; compute kt2 (E)
//  t3: +B4    -> 6          ; vmcnt(2) retires x+B3; compute kt3 (O)
//  cvt x -> other buffer; lgkmcnt(0); barrier.  Exit: [B4: 2]  (invariant)
#define ROUND(G, XI, CVTW)                                                     \
    {                                                                          \
        const char* bufr = sm.stage[(G) & 1];                                  \
        char* bufw = sm.stage[((G) + 1) & 1];                                  \
        bhO = gload_s8(bhp + (size_t)(4 * (G) + 1) * 8192);                    \
        blO = gload_s8(blp + (size_t)(4 * (G) + 1) * 8192);                    \
        asm volatile("s_waitcnt vmcnt(2)" ::: "memory");                       \
        __builtin_amdgcn_sched_barrier(0);                                     \
        MFMA_KT(bufr, 0, bhE, blE);                                            \
        bhE = gload_s8(bhp + (size_t)(4 * (G) + 2) * 8192);                    \
        blE = gload_s8(blp + (size_t)(4 * (G) + 2) * 8192);                    \
        XI;                                                                    \
        asm volatile("s_waitcnt vmcnt(4)" ::: "memory");                       \
        __builtin_amdgcn_sched_barrier(0);                                     \
        MFMA_KT(bufr, 1, bhO, blO);                                            \
        bhO = gload_s8(bhp + (size_t)(4 * (G) + 3) * 8192);                    \
        blO = gload_s8(blp + (size_t)(4 * (G) + 3) * 8192);                    \
        asm volatile("s_waitcnt vmcnt(4)" ::: "memory");                       \
        __builtin_amdgcn_sched_barrier(0);                                     \
        MFMA_KT(bufr, 2, bhE, blE);                                            \
        bhE = gload_s8(bhp + (size_t)(4 * (G) + 4) * 8192);                    \
        blE = gload_s8(blp + (size_t)(4 * (G) + 4) * 8192);                    \
        asm volatile("s_waitcnt vmcnt(2)" ::: "memory");                       \
        __builtin_amdgcn_sched_barrier(0);                                     \
        MFMA_KT(bufr, 3, bhO, blO);                                            \
        CVTW(bufw);                                                            \
        asm volatile("s_waitcnt lgkmcnt(0)" ::: "memory");                     \
        __builtin_amdgcn_sched_barrier(0);                                     \
        __builtin_amdgcn_s_barrier();                                          \
        __builtin_amdgcn_sched_barrier(0);                                     \
    }

__global__ __launch_bounds__(NTHREADS, 4)
void mlp_mfma_kernel(const float* __restrict__ x,
                     const char*  __restrict__ wsb,
                     const float* __restrict__ b1,
                     const float* __restrict__ w2,
                     const float* __restrict__ b2,
                     float* __restrict__ out)
{
    // stage[p]: hi image [0..16K), lo image [16K..32K). Element (row, ktl, half):
    //   off = row*128 + ((ktl ^ (row&3)) << 5) + ((half ^ ((row>>2)&1)) << 4)
    // Conflict-free on conv-writes AND frag-reads (8-lane groups span 8 quads).
    __shared__ union {
        char  stage[2][32768];    // 64 KB x tiles (K=64 window), double-buffered
        float hid[64 * 256];      // 64 KB epilogue half-tile (staging dead then)
    } sm;

    const int tid   = threadIdx.x;
    const int lane  = tid & 63;
    const int wv    = tid >> 6;         // 0..15
    const int ct    = wv & 7;           // column tile (B dedup'd within rg)
    const int rg    = wv >> 3;          // row group: rows rg*64 .. rg*64+63
    const int l31   = lane & 31;
    const int khalf = lane >> 5;
    const int row0  = blockIdx.x * BM;

    // stager map: thread -> row sr = tid>>3 (0..127), chunk sc = tid&7 (8 floats)
    const int sr  = tid >> 3;
    const int sc  = tid & 7;
    const int shf = sc & 1;                            // k-half within ktl
    const float* xs = x + (size_t)(row0 + sr) * IN_F;
    const int ssw = (sr >> 2) & 1;
    const int wo  = sr * 128 + (((sc >> 1) ^ (sr & 3)) & 3) * 32 + ((shf ^ ssw) << 4);
    const int wot = sr * 128 + ((sr & 3) << 5) + ((shf ^ ssw) << 4);   // ktl=0

    // frag read bases: row = rg*64 + rt*32 + l31 (asw = (l31>>2)&1 for both rt)
    const int txor = l31 & 3;
    const int asw  = (l31 >> 2) & 1;
    const int rb0  = (rg * 64 + l31) * 128 + ((khalf ^ asw) << 4);
    const int rb1  = rb0 + 4096;                       // +32 rows * 128 B

    // B image pointers for this wave's column tile
    const char* bhp = wsb + WS_W1H + ((size_t)ct * 64 + lane) * 16;
    const char* blp = wsb + WS_W1L + ((size_t)ct * 64 + lane) * 16;

    f32x16 acc0, acc1;
    #pragma unroll
    for (int r = 0; r < 16; ++r) { acc0[r] = 0.f; acc1[r] = 0.f; }

    short8 bhE, blE, bhO, blO;
    f32x4 s0, s1;

    // ---- prologue: x(round 0) 2 loads, B(kt0) 2 loads; cvt -> stage[0] ----
    s0 = gload_f4(xs + sc * 8);
    s1 = gload_f4(xs + sc * 8 + 4);
    bhE = gload_s8(bhp);
    blE = gload_s8(blp);
    asm volatile("s_waitcnt vmcnt(2)" ::: "memory");   // x landed; B(0) in flight
    __builtin_amdgcn_sched_barrier(0);
    CVT4W(sm.stage[0]);
    asm volatile("s_waitcnt lgkmcnt(0)" ::: "memory");
    __builtin_amdgcn_sched_barrier(0);
    __builtin_amdgcn_s_barrier();
    __builtin_amdgcn_sched_barrier(0);

    // ---- 12 rounds x 4 kt (kt 0..47), fully unrolled, then tail kt=48 ----
    ROUND(0,  XISSUE(0),  CVT4W)
    ROUND(1,  XISSUE(1),  CVT4W)
    ROUND(2,  XISSUE(2),  CVT4W)
    ROUND(3,  XISSUE(3),  CVT4W)
    ROUND(4,  XISSUE(4),  CVT4W)
    ROUND(5,  XISSUE(5),  CVT4W)
    ROUND(6,  XISSUE(6),  CVT4W)
    ROUND(7,  XISSUE(7),  CVT4W)
    ROUND(8,  XISSUE(8),  CVT4W)
    ROUND(9,  XISSUE(9),  CVT4W)
    ROUND(10, XISSUE(10), CVT4W)
    ROUND(11, XISSUET(),  CVTTW)
    {   // tail kt = 48 (stage[0] ktl 0; B(48) issued at round 11 t3, bank E)
        asm volatile("s_waitcnt vmcnt(0)" ::: "memory");
        __builtin_amdgcn_sched_barrier(0);
        MFMA_KT(sm.stage[0], 0, bhE, blE);
    }

    // ---- epilogue: two halves of 64 rows (hid aliases staging) ----
    const int rl    = tid >> 4;        // row 0..63 (within half)
    const int slice = tid & 15;        // 16 col-slices of 16
    const int sw2   = (rl & 7) << 2;

    __syncthreads();                   // all stage reads done before hid writes
    #pragma unroll
    for (int hf = 0; hf < 2; ++hf) {
        if (hf) __syncthreads();       // phase-2 reads of hf=0 done before rewrite
        // phase 1: bias + relu -> hid (only the owning row-group's waves write)
        if (rg == hf) {
            const int col = ct * 32 + l31;
            const float bv = b1[col];
            #pragma unroll
            for (int reg = 0; reg < 16; ++reg) {
                // C/D: col = lane&31, row = (reg&3) + 8*(reg>>2) + 4*(lane>>5)
                const int crow = (reg & 3) + 8 * (reg >> 2) + 4 * khalf;
                sm.hid[crow * 256 + (col ^ ((crow & 7) << 2))] =
                    fmaxf(acc0[reg] + bv, 0.f);
                const int drow = 32 + crow;
                sm.hid[drow * 256 + (col ^ ((drow & 7) << 2))] =
                    fmaxf(acc1[reg] + bv, 0.f);
            }
        }
        __syncthreads();
        // phase 2: logits + softmax for this half's 64 rows (16 slices/row)
        float lg[NCLS];
        #pragma unroll
        for (int k = 0; k < NCLS; ++k) lg[k] = 0.f;
        #pragma unroll
        for (int i = 0; i < 4; ++i) {
            const int ii  = (i + (slice >> 1)) & 3;    // rotation: spreads quads
            const int col = slice * 16 + ii * 4;
            const float4 h = *(const float4*)(sm.hid + rl * 256 + (col ^ sw2));
            #pragma unroll
            for (int k = 0; k < NCLS; ++k) {
                const float4 w = *(const float4*)(w2 + k * HID_F + col);
                lg[k] += h.x * w.x + h.y * w.y + h.z * w.z + h.w * w.w;
            }
        }
        #pragma unroll
        for (int k = 0; k < NCLS; ++k) {   // reduce 16 slices (lane bits 0..3)
            float v = lg[k];
            v += __shfl_xor(v, 1);
            v += __shfl_xor(v, 2);
            v += __shfl_xor(v, 4);
            v += __shfl_xor(v, 8);
            lg[k] = v + b2[k];
        }
        float mx = -1e30f;
        #pragma unroll
        for (int k = 0; k < NCLS; ++k) mx = fmaxf(mx, lg[k]);
        float s = 0.f;
        #pragma unroll
        for (int k = 0; k < NCLS; ++k) { lg[k] = __expf(lg[k] - mx); s += lg[k]; }
        const float inv = 1.f / s;
        // select lg[slice] without runtime register indexing (rule #20)
        const float va = (slice & 8)
            ? ((slice & 1) ? lg[9] : lg[8])
            : ((slice & 4)
                ? ((slice & 2) ? ((slice & 1) ? lg[7] : lg[6]) : ((slice & 1) ? lg[5] : lg[4]))
                : ((slice & 2) ? ((slice & 1) ? lg[3] : lg[2]) : ((slice & 1) ? lg[1] : lg[0])));
        if (slice < NCLS)
            out[(size_t)(row0 + hf * 64 + rl) * NCLS + slice] = va * inv;
    }
}

extern "C" void kernel_launch(void* const* d_in, const int* in_sizes, int n_in,
                              void* d_out, int out_size, void* d_ws, size_t ws_size,
                              hipStream_t stream)
{
    const float* x  = (const float*)d_in[0];
    const float* w1 = (const float*)d_in[1];
    const float* b1 = (const float*)d_in[2];
    const float* w2 = (const float*)d_in[3];
    const float* b2 = (const float*)d_in[4];
    float* out = (float*)d_out;

    // pre-pass: w1 -> split-bf16 32-wide frag images (98 blocks x 256)
    hipLaunchKernelGGL(prep_w1_kernel, dim3(98), dim3(256), 0, stream,
                       w1, (char*)d_ws);
    // main fused MLP: 256 blocks x 1024 threads, BM=128
    hipLaunchKernelGGL(mlp_mfma_kernel, dim3(BATCH_N / BM), dim3(NTHREADS), 0, stream,
                       x, (const char*)d_ws, b1, w2, b2, out);
}

// Round 10
// 190.761 us; speedup vs baseline: 1.0238x; 1.0238x over previous
//
#include <hip/hip_runtime.h>
#include <math.h>

#define BATCH_N   32768
#define IN_F      784
#define HID_F     256
#define NCLS      10
#define BM        128         // batch rows per block; grid = 256 = 1 block/CU
#define NTHREADS  512         // 8 waves: rp = wv>>2 (row half), cp = wv&3 (ct pair)

typedef __attribute__((ext_vector_type(8)))  short short8;   // 8 bf16 = one 32x32x16 operand frag
typedef __attribute__((ext_vector_type(4)))  float f32x4;
typedef __attribute__((ext_vector_type(16))) float f32x16;   // 32x32 accumulator

// d_ws: w1 as split-bf16 frag images for 32x32x16 B-operand (verified r6/r7):
//   slot s = (kt*8 + ct)*64 + lane, 16 B: elems j=0..7 =
//   w1[ct*32 + (lane&31)][kt*16 + (lane>>5)*8 + j]   (784 = 49*16: no padding)
#define WS_W1H 0
#define WS_W1L 401408          // 49*8*64*16

union S8U { short8 s; uint4 u; };

__device__ __forceinline__ void cvt8(float4 a, float4 b, short8* hi, short8* lo) {
    const unsigned M = 0xFFFF0000u;
    const unsigned ux = __float_as_uint(a.x), uy = __float_as_uint(a.y),
                   uz = __float_as_uint(a.z), uw = __float_as_uint(a.w),
                   vx = __float_as_uint(b.x), vy = __float_as_uint(b.y),
                   vz = __float_as_uint(b.z), vw = __float_as_uint(b.w);
    S8U h, l;
    h.u.x = (ux >> 16) | (uy & M);
    h.u.y = (uz >> 16) | (uw & M);
    h.u.z = (vx >> 16) | (vy & M);
    h.u.w = (vz >> 16) | (vw & M);
    const float rx = a.x - __uint_as_float(ux & M);
    const float ry = a.y - __uint_as_float(uy & M);
    const float rz = a.z - __uint_as_float(uz & M);
    const float rw = a.w - __uint_as_float(uw & M);
    const float sx = b.x - __uint_as_float(vx & M);
    const float sy = b.y - __uint_as_float(vy & M);
    const float sz = b.z - __uint_as_float(vz & M);
    const float sw_ = b.w - __uint_as_float(vw & M);
    l.u.x = (__float_as_uint(rx) >> 16) | (__float_as_uint(ry) & M);
    l.u.y = (__float_as_uint(rz) >> 16) | (__float_as_uint(rw) & M);
    l.u.z = (__float_as_uint(sx) >> 16) | (__float_as_uint(sy) & M);
    l.u.w = (__float_as_uint(sz) >> 16) | (__float_as_uint(sw_) & M);
    *hi = h.s; *lo = l.s;
}

__device__ __forceinline__ void cvt8v(f32x4 a, f32x4 b, short8* hi, short8* lo) {
    float4 fa = make_float4(a[0], a[1], a[2], a[3]);
    float4 fb = make_float4(b[0], b[1], b[2], b[3]);
    cvt8(fa, fb, hi, lo);
}

// ---- pre-pass: w1 -> split-bf16 32-wide frag images (verified r6/r7) ----
__global__ __launch_bounds__(256)
void prep_w1_kernel(const float* __restrict__ w1, char* __restrict__ ws) {
    const int s    = blockIdx.x * 256 + threadIdx.x;   // 49*8*64 = 25088, grid 98
    const int lane = s & 63, ct = (s >> 6) & 7, kt = s >> 9;
    const int n    = ct * 32 + (lane & 31);
    const int k0   = kt * 16 + (lane >> 5) * 8;
    const float* p = w1 + (size_t)n * IN_F + k0;
    const float4 a = *(const float4*)p;
    const float4 b = *(const float4*)(p + 4);
    short8 hi, lo;
    cvt8(a, b, &hi, &lo);
    *(short8*)(ws + WS_W1H + (size_t)s * 16) = hi;
    *(short8*)(ws + WS_W1L + (size_t)s * 16) = lo;
}

// inline-asm 16B loads; results consumed only after the matching manual vmcnt,
// and NEVER copied between registers while in flight (r5 contract).
__device__ __forceinline__ short8 gload_s8(const void* p) {
    short8 r;
    asm volatile("global_load_dwordx4 %0, %1, off" : "=v"(r) : "v"(p));
    return r;
}
__device__ __forceinline__ f32x4 gload_f4(const float* p) {
    f32x4 r;
    asm volatile("global_load_dwordx4 %0, %1, off" : "=v"(r) : "v"(p));
    return r;
}

#define MFMA32(A, B, C) __builtin_amdgcn_mfma_f32_32x32x16_bf16((A), (B), (C), 0, 0, 0)
#define SB __builtin_amdgcn_sched_barrier(0)

// one K-tile: 4 inline ds_read_b128 (2 rt x hi/lo) + 12 MFMAs (4 indep chains).
// LDS layout (r1-proven, conflict-free): off = row*128 + ((ktl*2+khalf)^(row&7))*16
#define MFMA_KT(BUF, T, S)                                                      \
    {                                                                           \
        const int sl = (((((T) << 1) | khalf) ^ l7) << 4);                      \
        const short8 ah0 = *(const short8*)((BUF) + arb0 + sl);                 \
        const short8 al0 = *(const short8*)((BUF) + 16384 + arb0 + sl);         \
        const short8 ah1 = *(const short8*)((BUF) + arb1 + sl);                 \
        const short8 al1 = *(const short8*)((BUF) + 16384 + arb1 + sl);         \
        __builtin_amdgcn_s_setprio(1);                                          \
        acc00 = MFMA32(ah0, bh0##S, acc00);                                     \
        acc01 = MFMA32(ah0, bh1##S, acc01);                                     \
        acc10 = MFMA32(ah1, bh0##S, acc10);                                     \
        acc11 = MFMA32(ah1, bh1##S, acc11);                                     \
        acc00 = MFMA32(al0, bh0##S, acc00);                                     \
        acc01 = MFMA32(al0, bh1##S, acc01);                                     \
        acc10 = MFMA32(al1, bh0##S, acc10);                                     \
        acc11 = MFMA32(al1, bh1##S, acc11);                                     \
        acc00 = MFMA32(ah0, bl0##S, acc00);                                     \
        acc01 = MFMA32(ah0, bl1##S, acc01);                                     \
        acc10 = MFMA32(ah1, bl0##S, acc10);                                     \
        acc11 = MFMA32(ah1, bl1##S, acc11);                                     \
        __builtin_amdgcn_s_setprio(0);                                          \
    }

// B issue: 4 loads (2 ct x hi/lo) into parity bank S (just consumed)
#define BISSUE(KT, S)                                                           \
    bh0##S = gload_s8(bhp + (size_t)(KT) * 8192);                               \
    bh1##S = gload_s8(bhp + (size_t)(KT) * 8192 + 1024);                        \
    bl0##S = gload_s8(blp + (size_t)(KT) * 8192);                               \
    bl1##S = gload_s8(blp + (size_t)(KT) * 8192 + 1024);

// x issue for next round window (16 floats/thread) / tail (8 floats/thread)
#define XISSUE(G) do {                                                          \
        s0 = gload_f4(xs + ((G) + 1) * 64 + sq * 8);                            \
        s1 = gload_f4(xs + ((G) + 1) * 64 + sq * 8 + 4);                        \
        s2 = gload_f4(xs + ((G) + 1) * 64 + 32 + sq * 8);                       \
        s3 = gload_f4(xs + ((G) + 1) * 64 + 32 + sq * 8 + 4);                   \
    } while (0)
#define XISSUET() do {                                                          \
        s0 = gload_f4(xs + 768 + (sq & 1) * 8);                                 \
        s1 = gload_f4(xs + 768 + (sq & 1) * 8 + 4);                             \
    } while (0)
// convert staged x: thread (sr, sq) wrote slots s8 = sq (ktl=sq>>1) and sq+4
#define CVT4W(BW) do {                                                          \
        short8 h0, l0, h1, l1;                                                  \
        cvt8v(s0, s1, &h0, &l0);                                                \
        cvt8v(s2, s3, &h1, &l1);                                                \
        *(short8*)((BW) + wo0)         = h0;                                    \
        *(short8*)((BW) + 16384 + wo0) = l0;                                    \
        *(short8*)((BW) + wo1)         = h1;                                    \
        *(short8*)((BW) + 16384 + wo1) = l1;                                    \
    } while (0)
#define CVTTW(BW) do {                                                          \
        short8 h0, l0;                                                          \
        cvt8v(s0, s1, &h0, &l0);                                                \
        if (sq < 2) {                                                           \
            *(short8*)((BW) + wo0)         = h0;                                \
            *(short8*)((BW) + 16384 + wo0) = l0;                                \
        }                                                                       \
    } while (0)

// Round of 4 kt. Entry invariant: outstanding = [B(4G):4].
// Ledger (oldest-first; 4 B loads/kt, 4 x loads at t1):
//  t0: +B1      -> 8 ; vmcnt(4) ret B0  ; kt0 (E)
//  t1: +B2,+x   -> 12; WT1=vmcnt(8) ret B1 ; kt1 (O)
//  t2: +B3      -> 12; WT2=vmcnt(8) ret B2 ; kt2 (E)
//  t3: +B4      -> 12; WT3=vmcnt(4) ret x+B3; kt3 (O)
//  cvt -> other buffer; lgkmcnt(0); barrier.  Exit: [B4:4]  (invariant)
// Tail round (x:2): WT1/WT2 = vmcnt(6), WT3 = vmcnt(4).
#define ROUND(G, WT1, WT2, WT3, XI, CVTW)                                       \
    {                                                                           \
        const char* bufr = sm.stage[(G) & 1];                                   \
        char* bufw = sm.stage[((G) + 1) & 1];                                   \
        BISSUE(4 * (G) + 1, O)                                                  \
        asm volatile("s_waitcnt vmcnt(4)" ::: "memory");                        \
        SB;                                                                     \
        MFMA_KT(bufr, 0, E)                                                     \
        BISSUE(4 * (G) + 2, E)                                                  \
        XI;                                                                     \
        asm volatile(WT1 ::: "memory");                                         \
        SB;                                                                     \
        MFMA_KT(bufr, 1, O)                                                     \
        BISSUE(4 * (G) + 3, O)                                                  \
        asm volatile(WT2 ::: "memory");                                         \
        SB;                                                                     \
        MFMA_KT(bufr, 2, E)                                                     \
        BISSUE(4 * (G) + 4, E)                                                  \
        asm volatile(WT3 ::: "memory");                                         \
        SB;                                                                     \
        MFMA_KT(bufr, 3, O)                                                     \
        CVTW(bufw);                                                             \
        asm volatile("s_waitcnt lgkmcnt(0)" ::: "memory");                      \
        SB;                                                                     \
        __builtin_amdgcn_s_barrier();                                           \
        SB;                                                                     \
    }

__global__ __launch_bounds__(NTHREADS, 2)
void mlp_mfma_kernel(const float* __restrict__ x,
                     const char*  __restrict__ wsb,
                     const float* __restrict__ b1,
                     const float* __restrict__ w2,
                     const float* __restrict__ b2,
                     float* __restrict__ out)
{
    // stage[p]: hi image [0,16K), lo image [16K,32K).
    //   element (row, ktl, khalf): off = row*128 + ((ktl*2+khalf)^(row&7))*16
    __shared__ union {
        char  stage[2][32768];    // 64 KB x tiles (K=64 window), double-buffered
        float hid[64 * 256];      // 64 KB epilogue half-tile (staging dead then)
    } sm;

    const int tid   = threadIdx.x;
    const int lane  = tid & 63;
    const int wv    = tid >> 6;
    const int cp    = wv & 3;           // ct pair: cols (cp*2+c)*32 + l31
    const int rp    = wv >> 2;          // row half: rows rp*64 + rt*32 + l31
    const int l31   = lane & 31;
    const int khalf = lane >> 5;
    const int l7    = l31 & 7;
    const int row0  = blockIdx.x * BM;

    // stager map: thread -> row sr = tid>>2 (0..127), quarter sq = tid&3;
    // handles slots s8 = sq (ktl=sq>>1, khalf=sq&1) and s8 = sq+4 (ktl+2)
    const int sr  = tid >> 2;
    const int sq  = tid & 3;
    const float* xs = x + (size_t)(row0 + sr) * IN_F;
    const int wo0 = sr * 128 + ((sq ^ (sr & 7)) << 4);
    const int wo1 = sr * 128 + (((sq + 4) ^ (sr & 7)) << 4);

    // frag read bases: rt0 rows rp*64+l31, rt1 +32 rows (+4096 B)
    const int arb0 = (rp * 64 + l31) * 128;
    const int arb1 = arb0 + 4096;

    // B image pointers: this wave's 2 column tiles cp*2, cp*2+1
    const char* bhp = wsb + WS_W1H + ((size_t)(cp * 2) * 64 + lane) * 16;
    const char* blp = wsb + WS_W1L + ((size_t)(cp * 2) * 64 + lane) * 16;

    f32x16 acc00, acc01, acc10, acc11;
    #pragma unroll
    for (int r = 0; r < 16; ++r) { acc00[r] = 0.f; acc01[r] = 0.f; acc10[r] = 0.f; acc11[r] = 0.f; }

    short8 bh0E, bh1E, bl0E, bl1E, bh0O, bh1O, bl0O, bl1O;
    f32x4 s0, s1, s2, s3;

    // ---- prologue: x(round 0) 4 loads; B(0)->E 4 loads; cvt -> stage[0] ----
    s0 = gload_f4(xs + sq * 8);
    s1 = gload_f4(xs + sq * 8 + 4);
    s2 = gload_f4(xs + 32 + sq * 8);
    s3 = gload_f4(xs + 32 + sq * 8 + 4);
    BISSUE(0, E)
    asm volatile("s_waitcnt vmcnt(4)" ::: "memory");   // x landed; B0 in flight
    SB;
    CVT4W(sm.stage[0]);
    asm volatile("s_waitcnt lgkmcnt(0)" ::: "memory");
    SB;
    __builtin_amdgcn_s_barrier();
    SB;

    // ---- 12 rounds x 4 kt (kt 0..47), fully unrolled, then tail kt=48 ----
    ROUND(0,  "s_waitcnt vmcnt(8)", "s_waitcnt vmcnt(8)", "s_waitcnt vmcnt(4)", XISSUE(0),  CVT4W)
    ROUND(1,  "s_waitcnt vmcnt(8)", "s_waitcnt vmcnt(8)", "s_waitcnt vmcnt(4)", XISSUE(1),  CVT4W)
    ROUND(2,  "s_waitcnt vmcnt(8)", "s_waitcnt vmcnt(8)", "s_waitcnt vmcnt(4)", XISSUE(2),  CVT4W)
    ROUND(3,  "s_waitcnt vmcnt(8)", "s_waitcnt vmcnt(8)", "s_waitcnt vmcnt(4)", XISSUE(3),  CVT4W)
    ROUND(4,  "s_waitcnt vmcnt(8)", "s_waitcnt vmcnt(8)", "s_waitcnt vmcnt(4)", XISSUE(4),  CVT4W)
    ROUND(5,  "s_waitcnt vmcnt(8)", "s_waitcnt vmcnt(8)", "s_waitcnt vmcnt(4)", XISSUE(5),  CVT4W)
    ROUND(6,  "s_waitcnt vmcnt(8)", "s_waitcnt vmcnt(8)", "s_waitcnt vmcnt(4)", XISSUE(6),  CVT4W)
    ROUND(7,  "s_waitcnt vmcnt(8)", "s_waitcnt vmcnt(8)", "s_waitcnt vmcnt(4)", XISSUE(7),  CVT4W)
    ROUND(8,  "s_waitcnt vmcnt(8)", "s_waitcnt vmcnt(8)", "s_waitcnt vmcnt(4)", XISSUE(8),  CVT4W)
    ROUND(9,  "s_waitcnt vmcnt(8)", "s_waitcnt vmcnt(8)", "s_waitcnt vmcnt(4)", XISSUE(9),  CVT4W)
    ROUND(10, "s_waitcnt vmcnt(8)", "s_waitcnt vmcnt(8)", "s_waitcnt vmcnt(4)", XISSUE(10), CVT4W)
    ROUND(11, "s_waitcnt vmcnt(6)", "s_waitcnt vmcnt(6)", "s_waitcnt vmcnt(4)", XISSUET(),  CVTTW)
    {   // tail kt = 48 (stage[0] ktl 0; B(48)->E issued at round 11 t3)
        asm volatile("s_waitcnt vmcnt(0)" ::: "memory");
        SB;
        MFMA_KT(sm.stage[0], 0, E)
    }

    // ---- epilogue: two halves of 64 rows (phase-2 r7 verbatim) ----
    const int rl    = tid >> 3;        // row 0..63 (within half)
    const int slice = tid & 7;         // 8 col-slices of 32
    const int sw2   = (rl & 7) << 2;

    #pragma unroll
    for (int half = 0; half < 2; ++half) {
        __syncthreads();               // half0: stage reads done; half1: phase-2 reads done
        // phase 1: bias + relu -> hid; only waves with rp == half write
        if (rp == half) {
            #pragma unroll
            for (int c = 0; c < 2; ++c) {
                const int col = (cp * 2 + c) * 32 + l31;
                const float bv = b1[col];
                #pragma unroll
                for (int reg = 0; reg < 16; ++reg) {
                    // C/D: col = lane&31, row = (reg&3) + 8*(reg>>2) + 4*(lane>>5)
                    const int r0 = (reg & 3) + 8 * (reg >> 2) + 4 * khalf;
                    const float v0 = (c == 0) ? acc00[reg] : acc01[reg];
                    sm.hid[r0 * 256 + (col ^ ((r0 & 7) << 2))] = fmaxf(v0 + bv, 0.f);
                    const int r1 = 32 + r0;
                    const float v1 = (c == 0) ? acc10[reg] : acc11[reg];
                    sm.hid[r1 * 256 + (col ^ ((r1 & 7) << 2))] = fmaxf(v1 + bv, 0.f);
                }
            }
        }
        __syncthreads();
        // phase 2: logits + softmax for this half's 64 rows
        float lg[NCLS];
        #pragma unroll
        for (int k = 0; k < NCLS; ++k) lg[k] = 0.f;
        #pragma unroll
        for (int i = 0; i < 8; ++i) {
            const int ii  = ((i + slice) & 7) * 4;     // rotation: spreads bank quads
            const int col = slice * 32 + ii;
            const float4 h = *(const float4*)(sm.hid + rl * 256 + (slice * 32 + (ii ^ sw2)));
            #pragma unroll
            for (int k = 0; k < NCLS; ++k) {
                const float4 w = *(const float4*)(w2 + k * HID_F + col);
                lg[k] += h.x * w.x + h.y * w.y + h.z * w.z + h.w * w.w;
            }
        }
        #pragma unroll
        for (int k = 0; k < NCLS; ++k) {   // reduce 8 slices (lane bits 0..2)
            float v = lg[k];
            v += __shfl_xor(v, 1);
            v += __shfl_xor(v, 2);
            v += __shfl_xor(v, 4);
            lg[k] = v + b2[k];
        }
        float mx = -1e30f;
        #pragma unroll
        for (int k = 0; k < NCLS; ++k) mx = fmaxf(mx, lg[k]);
        float s = 0.f;
        #pragma unroll
        for (int k = 0; k < NCLS; ++k) { lg[k] = __expf(lg[k] - mx); s += lg[k]; }
        const float inv = 1.f / s;
        const float va = (slice & 4)
            ? ((slice & 2) ? ((slice & 1) ? lg[7] : lg[6]) : ((slice & 1) ? lg[5] : lg[4]))
            : ((slice & 2) ? ((slice & 1) ? lg[3] : lg[2]) : ((slice & 1) ? lg[1] : lg[0]));
        const float vb = (slice & 1) ? lg[9] : lg[8];
        float* o = out + (size_t)(row0 + half * 64 + rl) * NCLS;
        o[slice] = va * inv;
        if (slice < 2) o[8 + slice] = vb * inv;
    }
}

extern "C" void kernel_launch(void* const* d_in, const int* in_sizes, int n_in,
                              void* d_out, int out_size, void* d_ws, size_t ws_size,
                              hipStream_t stream)
{
    const float* x  = (const float*)d_in[0];
    const float* w1 = (const float*)d_in[1];
    const float* b1 = (const float*)d_in[2];
    const float* w2 = (const float*)d_in[3];
    const float* b2 = (const float*)d_in[4];
    float* out = (float*)d_out;

    // pre-pass: w1 -> split-bf16 32-wide frag images (98 blocks x 256)
    hipLaunchKernelGGL(prep_w1_kernel, dim3(98), dim3(256), 0, stream,
                       w1, (char*)d_ws);
    // main fused MLP: 256 blocks x 512 threads, BM=128
    hipLaunchKernelGGL(mlp_mfma_kernel, dim3(BATCH_N / BM), dim3(NTHREADS), 0, stream,
                       x, (const char*)d_ws, b1, w2, b2, out);
}